// Round 3
// baseline (102.277 us; speedup 1.0000x reference)
//
#include <hip/hip_runtime.h>
#include <stdint.h>

#define TT 64
#define BB 128
#define VV 4880
#define NF4 (VV / 4)          // 1220 float4 per row
#define NROWS (TT * BB)       // 8192
#define LOG_EPS_F 1e-8f
#define CAP 256               // max stored candidates per row
#define PCAP 64               // max stored positive candidates per row
#define NBUCKET 64
#define NQ 9
#define THR0 0.98f

// Pack (value, row-local idx) so that u64 max-compare == (value desc, idx asc).
// y_hat > 0 so float bits are monotonic in value. idx < 4880 fits in 13 bits.
__device__ __forceinline__ uint64_t mkkey(float v, int idx) {
  return ((uint64_t)__float_as_uint(v) << 13) | (uint64_t)(8191 - idx);
}

__global__ __launch_bounds__(256) void pass_kernel(
    const float* __restrict__ yhat, const float* __restrict__ yy,
    const float* __restrict__ length, float* __restrict__ bucket) {
  __shared__ uint64_t cand[4][CAP];
  __shared__ uint64_t pcand[4][PCAP];
  __shared__ int cnt_sh[4];
  __shared__ int pcnt_sh[4];
  __shared__ int retry_sh;

  const int wid  = threadIdx.x >> 6;    // wave 0..3
  const int lane = threadIdx.x & 63;
  const int row  = blockIdx.x * 4 + wid;   // row = t*B + b
  const int b    = row & (BB - 1);
  const float4* h4 = (const float4*)(yhat + (size_t)row * VV);
  const float4* y4 = (const float4*)(yy   + (size_t)row * VV);

  if (threadIdx.x < 4) { cnt_sh[threadIdx.x] = 0; pcnt_sh[threadIdx.x] = 0; }
  if (threadIdx.x == 0) retry_sh = 0;
  __syncthreads();

  float logsum = 0.0f;   // sum of log(selected); ce = -logsum
  float nposf  = 0.0f;
  float thr    = THR0;

  auto ins = [&](float v, float yv, int idx) {
    uint64_t key = mkkey(v, idx);
    int s = atomicAdd(&cnt_sh[wid], 1);
    if (s < CAP) cand[wid][s] = key;
    if (yv != 0.0f) {
      int sp = atomicAdd(&pcnt_sh[wid], 1);
      if (sp < PCAP) pcand[wid][sp] = key;
    }
  };
  // full processing of one float4 pair (BCE via product-of-4 + candidates)
  auto procf4 = [&](float4 h, float4 v, int base) {
    float a0 = ((v.x != 0.0f) ? h.x : (1.0f - h.x)) + LOG_EPS_F;
    float a1 = ((v.y != 0.0f) ? h.y : (1.0f - h.y)) + LOG_EPS_F;
    float a2 = ((v.z != 0.0f) ? h.z : (1.0f - h.z)) + LOG_EPS_F;
    float a3 = ((v.w != 0.0f) ? h.w : (1.0f - h.w)) + LOG_EPS_F;
    logsum += __logf((a0 * a1) * (a2 * a3));   // product >= 1e-16, no underflow
    nposf  += (v.x + v.y) + (v.z + v.w);       // y is exactly 0.0/1.0
    if (h.x > thr) ins(h.x, v.x, base);
    if (h.y > thr) ins(h.y, v.y, base + 1);
    if (h.z > thr) ins(h.z, v.z, base + 2);
    if (h.w > thr) ins(h.w, v.w, base + 3);
  };

  // ---- main scan: 20 chunks of 64 float4, software-pipelined in 5 batches ----
  // chunk c: this lane handles f = lane + 64*c (f < 1220; only chunk 19 partial)
  float4 ha0, ha1, ha2, ha3, va0, va1, va2, va3;   // buffer A
  float4 hb0, hb1, hb2, hb3, vb0, vb1, vb2, vb3;   // buffer B

#define LD(H, V, c) { int f_ = lane + 64 * (c); H = h4[f_]; V = y4[f_]; }
#define PROC(H0,V0,H1,V1,H2,V2,H3,V3,c0) \
  procf4(H0, V0, 4 * (lane + 64 * (c0)));      \
  procf4(H1, V1, 4 * (lane + 64 * ((c0)+1)));  \
  procf4(H2, V2, 4 * (lane + 64 * ((c0)+2)));  \
  procf4(H3, V3, 4 * (lane + 64 * ((c0)+3)));

  LD(ha0, va0, 0) LD(ha1, va1, 1) LD(ha2, va2, 2) LD(ha3, va3, 3)
  LD(hb0, vb0, 4) LD(hb1, vb1, 5) LD(hb2, vb2, 6) LD(hb3, vb3, 7)
  PROC(ha0, va0, ha1, va1, ha2, va2, ha3, va3, 0)
  LD(ha0, va0, 8) LD(ha1, va1, 9) LD(ha2, va2, 10) LD(ha3, va3, 11)
  PROC(hb0, vb0, hb1, vb1, hb2, vb2, hb3, vb3, 4)
  LD(hb0, vb0, 12) LD(hb1, vb1, 13) LD(hb2, vb2, 14) LD(hb3, vb3, 15)
  PROC(ha0, va0, ha1, va1, ha2, va2, ha3, va3, 8)
  // final batch: chunks 16-18 full, chunk 19 predicated (lanes 0-3 only)
  LD(ha0, va0, 16) LD(ha1, va1, 17) LD(ha2, va2, 18)
  {
    const bool act = (lane < 4);
    const int f_ = act ? (1216 + lane) : 1216;
    ha3 = h4[f_]; va3 = y4[f_];
    if (!act) { ha3 = make_float4(0,0,0,0); va3 = make_float4(0,0,0,0); }
  }
  PROC(hb0, vb0, hb1, vb1, hb2, vb2, hb3, vb3, 12)
  procf4(ha0, va0, 4 * (lane + 64 * 16));
  procf4(ha1, va1, 4 * (lane + 64 * 17));
  procf4(ha2, va2, 4 * (lane + 64 * 18));
  procf4(ha3, va3, 4 * (lane + 64 * 19));  // OOB lanes: a=1.0 exactly -> log 0
#undef LD
#undef PROC
  __syncthreads();

  int  cnt  = cnt_sh[wid];
  int  pcnt = pcnt_sh[wid];
  bool done = (cnt >= 20 && cnt <= CAP);
  if (!done && lane == 0) retry_sh = 1;
  __syncthreads();

  // ---- cold retry path (block-uniform loop; never taken on this data) ----
  if (retry_sh) {
    for (int attempt = 1; attempt < 6; ++attempt) {
      if (!done) thr = (cnt < 20) ? 1.0f - (1.0f - thr) * 4.0f
                                  : 1.0f - (1.0f - thr) * 0.25f;
      __syncthreads();
      if (!done && lane == 0) { cnt_sh[wid] = 0; pcnt_sh[wid] = 0; }
      if (threadIdx.x == 0) retry_sh = 0;
      __syncthreads();
      if (!done) {
        for (int f = lane; f < NF4; f += 64) {
          float4 h = h4[f], v = y4[f];
          if (h.x > thr) ins(h.x, v.x, 4 * f);
          if (h.y > thr) ins(h.y, v.y, 4 * f + 1);
          if (h.z > thr) ins(h.z, v.z, 4 * f + 2);
          if (h.w > thr) ins(h.w, v.w, 4 * f + 3);
        }
      }
      __syncthreads();
      if (!done) {
        cnt = cnt_sh[wid]; pcnt = pcnt_sh[wid];
        done = (cnt >= 20 && cnt <= CAP);
      }
      if (!done && lane == 0) retry_sh = 1;
      __syncthreads();
      if (!retry_sh) break;
    }
  }
  if (cnt > CAP)   cnt  = CAP;
  if (pcnt > PCAP) pcnt = PCAP;

  // ---- rank each positive candidate: rank = #{cand keys > key(p)} ----
  float tpk[4] = {0.f, 0.f, 0.f, 0.f};
  for (int p = 0; p < pcnt; ++p) {
    uint64_t pk = pcand[wid][p];
    int c = 0;
    for (int j = lane; j < cnt; j += 64) c += (cand[wid][j] > pk) ? 1 : 0;
    #pragma unroll
    for (int s = 32; s >= 1; s >>= 1) c += __shfl_xor(c, s, 64);
    tpk[0] += (c < 5);  tpk[1] += (c < 10);
    tpk[2] += (c < 15); tpk[3] += (c < 20);
  }

  // ---- wave reductions for ce and n_pos ----
  #pragma unroll
  for (int s = 32; s >= 1; s >>= 1) {
    logsum += __shfl_xor(logsum, s, 64);
    nposf  += __shfl_xor(nposf, s, 64);
  }

  if (lane == 0) {
    float* bk = bucket + (size_t)(row & (NBUCKET - 1)) * NQ;
    float ce = -logsum / (length[b] * (float)BB);
    atomicAdd(bk + 0, ce);
    atomicAdd(bk + 1, tpk[0]);
    atomicAdd(bk + 2, tpk[1]);
    atomicAdd(bk + 3, tpk[2]);
    atomicAdd(bk + 4, tpk[3]);
    atomicAdd(bk + 5, nposf);
    atomicAdd(bk + 6, nposf);
    atomicAdd(bk + 7, nposf);
    atomicAdd(bk + 8, nposf);
  }
}

__global__ __launch_bounds__(64) void reduce_kernel(const float* __restrict__ bucket,
                                                    float* __restrict__ out) {
  const int lane = threadIdx.x;  // 64 lanes, one bucket each
  float acc[NQ];
  #pragma unroll
  for (int q = 0; q < NQ; ++q) acc[q] = bucket[lane * NQ + q];
  #pragma unroll
  for (int q = 0; q < NQ; ++q) {
    #pragma unroll
    for (int s = 32; s >= 1; s >>= 1) acc[q] += __shfl_xor(acc[q], s, 64);
  }
  if (lane == 0) {
    #pragma unroll
    for (int q = 0; q < NQ; ++q) out[q] = acc[q];
  }
}

extern "C" void kernel_launch(void* const* d_in, const int* in_sizes, int n_in,
                              void* d_out, int out_size, void* d_ws, size_t ws_size,
                              hipStream_t stream) {
  const float* yhat = (const float*)d_in[0];
  const float* yy   = (const float*)d_in[1];
  const float* len  = (const float*)d_in[2];
  float* out    = (float*)d_out;
  float* bucket = (float*)d_ws;   // NBUCKET*NQ floats = 2304 B

  hipMemsetAsync(bucket, 0, NBUCKET * NQ * sizeof(float), stream);
  pass_kernel<<<NROWS / 4, 256, 0, stream>>>(yhat, yy, len, bucket);
  reduce_kernel<<<1, 64, 0, stream>>>(bucket, out);
}

// Round 4
// 95.533 us; speedup vs baseline: 1.0706x; 1.0706x over previous
//
#include <hip/hip_runtime.h>
#include <stdint.h>

#define TT 64
#define BB 128
#define VV 4880
#define NF4 (VV / 4)          // 1220 float4 per row
#define NROWS (TT * BB)       // 8192
#define LOG_EPS_F 1e-8f
#define CAP 256               // max stored candidates per row
#define PCAP 64               // max stored positive candidates per row
#define NBUCKET 64
#define NQ 9
#define THR0 0.98f

// Pack (value, row-local idx) so that u64 max-compare == (value desc, idx asc).
// y_hat > 0 so float bits are monotonic in value. idx < 4880 fits in 13 bits.
__device__ __forceinline__ uint64_t mkkey(float v, int idx) {
  return ((uint64_t)__float_as_uint(v) << 13) | (uint64_t)(8191 - idx);
}

__device__ __forceinline__ int lane_prefix(unsigned long long m) {
  return __builtin_amdgcn_mbcnt_hi((unsigned)(m >> 32),
         __builtin_amdgcn_mbcnt_lo((unsigned)m, 0));
}

__global__ __launch_bounds__(256) void pass_kernel(
    const float* __restrict__ yhat, const float* __restrict__ yy,
    const float* __restrict__ length, float* __restrict__ bucket) {
  __shared__ uint64_t cand[4][CAP];
  __shared__ uint64_t pcand[4][PCAP];

  const int wid  = threadIdx.x >> 6;    // wave 0..3
  const int lane = threadIdx.x & 63;
  const int row  = blockIdx.x * 4 + wid;   // row = t*B + b
  const int b    = row & (BB - 1);
  const float4* h4 = (const float4*)(yhat + (size_t)row * VV);
  const float4* y4 = (const float4*)(yy   + (size_t)row * VV);
  uint64_t* cd = cand[wid];             // this wave's private slices
  uint64_t* pc = pcand[wid];

  float logsum = 0.0f;   // sum of log(selected); ce = -logsum
  float nposf  = 0.0f;
  float thr    = THR0;
  int   cnt    = 0;      // wave-uniform candidate count (scalar)
  int   pcnt   = 0;      // wave-uniform positive-candidate count

  // ballot-compaction insert: no LDS atomics, no round-trip dependency
  auto slot = [&](float v, float yv, int idx) {
    bool take = v > thr;
    unsigned long long m = __ballot(take);
    if (m) {
      if (take) {
        int s = cnt + lane_prefix(m);
        if (s < CAP) cd[s] = mkkey(v, idx);
      }
      cnt += __popcll(m);
      bool pt = take && (yv != 0.0f);
      unsigned long long pm = __ballot(pt);
      if (pm) {
        if (pt) {
          int sp = pcnt + lane_prefix(pm);
          if (sp < PCAP) pc[sp] = mkkey(v, idx);
        }
        pcnt += __popcll(pm);
      }
    }
  };
  // full processing of one float4 pair (BCE via product-of-4 + candidates)
  auto procf4 = [&](float4 h, float4 v, int base) {
    float a0 = ((v.x != 0.0f) ? h.x : (1.0f - h.x)) + LOG_EPS_F;
    float a1 = ((v.y != 0.0f) ? h.y : (1.0f - h.y)) + LOG_EPS_F;
    float a2 = ((v.z != 0.0f) ? h.z : (1.0f - h.z)) + LOG_EPS_F;
    float a3 = ((v.w != 0.0f) ? h.w : (1.0f - h.w)) + LOG_EPS_F;
    logsum += __logf((a0 * a1) * (a2 * a3));   // product >= 1e-16, no underflow
    nposf  += (v.x + v.y) + (v.z + v.w);       // y is exactly 0.0/1.0
    slot(h.x, v.x, base);     slot(h.y, v.y, base + 1);
    slot(h.z, v.z, base + 2); slot(h.w, v.w, base + 3);
  };

  // ---- main scan: R2 structure (batched loads, modest VGPR) ----
  #pragma unroll 1
  for (int i = 0; i < 16; i += 4) {
    const int f = lane + 64 * i;
    float4 h0 = h4[f], h1 = h4[f + 64], h2 = h4[f + 128], h3 = h4[f + 192];
    float4 v0 = y4[f], v1 = y4[f + 64], v2 = y4[f + 128], v3 = y4[f + 192];
    procf4(h0, v0, 4 * f);
    procf4(h1, v1, 4 * (f + 64));
    procf4(h2, v2, 4 * (f + 128));
    procf4(h3, v3, 4 * (f + 192));
  }
  #pragma unroll
  for (int i = 16; i < 19; ++i) {
    const int f = lane + 64 * i;
    float4 h0 = h4[f], v0 = y4[f];
    procf4(h0, v0, 4 * f);
  }
  {
    // chunk 19: only lanes 0-3 are in range; others fed neutral values
    const bool act = (lane < 4);
    const int f_ = act ? (1216 + lane) : 1216;
    float4 h0 = h4[f_], v0 = y4[f_];
    if (!act) { h0 = make_float4(0, 0, 0, 0); v0 = make_float4(0, 0, 0, 0); }
    procf4(h0, v0, 4 * (1216 + lane));   // inactive: a=1.0 -> log 0, no take
  }

  // ---- per-wave retry (wave-uniform; never taken on this data) ----
  int attempt = 0;
  while (!(cnt >= 20 && cnt <= CAP) && attempt < 6) {
    thr = (cnt < 20) ? 1.0f - (1.0f - thr) * 4.0f
                     : 1.0f - (1.0f - thr) * 0.25f;
    cnt = 0; pcnt = 0;
    for (int f = lane; f < NF4; f += 64) {
      float4 h = h4[f], v = y4[f];
      slot(h.x, v.x, 4 * f);     slot(h.y, v.y, 4 * f + 1);
      slot(h.z, v.z, 4 * f + 2); slot(h.w, v.w, 4 * f + 3);
    }
    ++attempt;
  }
  if (cnt > CAP)   cnt  = CAP;
  if (pcnt > PCAP) pcnt = PCAP;

  // ---- rank each positive candidate: rank = #{cand keys > key(p)} ----
  float tpk[4] = {0.f, 0.f, 0.f, 0.f};
  for (int p = 0; p < pcnt; ++p) {
    uint64_t pk = pc[p];
    int c = 0;
    for (int j = lane; j < cnt; j += 64) c += (cd[j] > pk) ? 1 : 0;
    #pragma unroll
    for (int s = 32; s >= 1; s >>= 1) c += __shfl_xor(c, s, 64);
    tpk[0] += (c < 5);  tpk[1] += (c < 10);
    tpk[2] += (c < 15); tpk[3] += (c < 20);
  }

  // ---- wave reductions for ce and n_pos ----
  #pragma unroll
  for (int s = 32; s >= 1; s >>= 1) {
    logsum += __shfl_xor(logsum, s, 64);
    nposf  += __shfl_xor(nposf, s, 64);
  }

  if (lane == 0) {
    float* bk = bucket + (size_t)(row & (NBUCKET - 1)) * NQ;
    float ce = -logsum / (length[b] * (float)BB);
    atomicAdd(bk + 0, ce);
    atomicAdd(bk + 1, tpk[0]);
    atomicAdd(bk + 2, tpk[1]);
    atomicAdd(bk + 3, tpk[2]);
    atomicAdd(bk + 4, tpk[3]);
    atomicAdd(bk + 5, nposf);
    atomicAdd(bk + 6, nposf);
    atomicAdd(bk + 7, nposf);
    atomicAdd(bk + 8, nposf);
  }
}

__global__ __launch_bounds__(64) void reduce_kernel(const float* __restrict__ bucket,
                                                    float* __restrict__ out) {
  const int lane = threadIdx.x;  // 64 lanes, one bucket each
  float acc[NQ];
  #pragma unroll
  for (int q = 0; q < NQ; ++q) acc[q] = bucket[lane * NQ + q];
  #pragma unroll
  for (int q = 0; q < NQ; ++q) {
    #pragma unroll
    for (int s = 32; s >= 1; s >>= 1) acc[q] += __shfl_xor(acc[q], s, 64);
  }
  if (lane == 0) {
    #pragma unroll
    for (int q = 0; q < NQ; ++q) out[q] = acc[q];
  }
}

extern "C" void kernel_launch(void* const* d_in, const int* in_sizes, int n_in,
                              void* d_out, int out_size, void* d_ws, size_t ws_size,
                              hipStream_t stream) {
  const float* yhat = (const float*)d_in[0];
  const float* yy   = (const float*)d_in[1];
  const float* len  = (const float*)d_in[2];
  float* out    = (float*)d_out;
  float* bucket = (float*)d_ws;   // NBUCKET*NQ floats = 2304 B

  hipMemsetAsync(bucket, 0, NBUCKET * NQ * sizeof(float), stream);
  pass_kernel<<<NROWS / 4, 256, 0, stream>>>(yhat, yy, len, bucket);
  reduce_kernel<<<1, 64, 0, stream>>>(bucket, out);
}